// Round 1
// baseline (8583.348 us; speedup 1.0000x reference)
//
#include <hip/hip_runtime.h>
#include <stdint.h>

#define TT 2048
#define HH 2048
#define II 7168
#define EE 8

typedef _Float16 v8h __attribute__((ext_vector_type(8)));
typedef _Float16 v4h __attribute__((ext_vector_type(4)));
typedef float    v4f __attribute__((ext_vector_type(4)));

// async global->LDS, 16B per lane. LDS dest must be wave-uniform base; HW adds lane*16.
__device__ __forceinline__ void gld16(const void* g, void* l) {
    __builtin_amdgcn_global_load_lds(
        (const __attribute__((address_space(1))) uint32_t*)g,
        (__attribute__((address_space(3))) uint32_t*)l,
        16, 0, 0);
}

// ---------------- zero out + counters ----------------
__global__ void k_zero(float* __restrict__ out, int* __restrict__ counts) {
    int i = blockIdx.x * 256 + threadIdx.x;           // 4096 blocks -> 1,048,576 float4 = 4.19M floats
    float4 z = make_float4(0.f, 0.f, 0.f, 0.f);
    reinterpret_cast<float4*>(out)[i] = z;
    if (blockIdx.x == 0 && threadIdx.x < EE) counts[threadIdx.x] = 0;
}

// ---------------- x fp32 -> fp16 ----------------
__global__ void k_cvt(const float* __restrict__ x, _Float16* __restrict__ xh) {
    int i = blockIdx.x * 256 + threadIdx.x;           // 4096 blocks
    float4 v = reinterpret_cast<const float4*>(x)[i];
    v4h h;
    h[0] = (_Float16)v.x; h[1] = (_Float16)v.y;
    h[2] = (_Float16)v.z; h[3] = (_Float16)v.w;
    reinterpret_cast<v4h*>(xh)[i] = h;
}

// ---------------- router: logits, softmax, top-2, renorm ----------------
__global__ __launch_bounds__(256) void k_router(const float* __restrict__ x,
                                                const float* __restrict__ gw,
                                                int* __restrict__ sel,
                                                float* __restrict__ wsel,
                                                int* __restrict__ counts) {
    int t = blockIdx.x, tid = threadIdx.x;
    float acc[EE];
#pragma unroll
    for (int e = 0; e < EE; ++e) acc[e] = 0.f;
    for (int h = tid; h < HH; h += 256) {
        float xv = x[(size_t)t * HH + h];
#pragma unroll
        for (int e = 0; e < EE; ++e) acc[e] += xv * gw[e * HH + h];
    }
    __shared__ float red[EE][256];
#pragma unroll
    for (int e = 0; e < EE; ++e) red[e][tid] = acc[e];
    __syncthreads();
    for (int s = 128; s > 0; s >>= 1) {
        if (tid < s) {
#pragma unroll
            for (int e = 0; e < EE; ++e) red[e][tid] += red[e][tid + s];
        }
        __syncthreads();
    }
    if (tid == 0) {
        float l[EE], p[EE], mx = -1e30f;
#pragma unroll
        for (int e = 0; e < EE; ++e) { l[e] = red[e][0]; mx = fmaxf(mx, l[e]); }
#pragma unroll
        for (int e = 0; e < EE; ++e) p[e] = __expf(l[e] - mx);
        int i0 = 0;
#pragma unroll
        for (int e = 1; e < EE; ++e) if (p[e] > p[i0]) i0 = e;   // strict >: earliest index on tie (lax.top_k)
        int i1 = (i0 == 0) ? 1 : 0;
#pragma unroll
        for (int e = 0; e < EE; ++e) if (e != i0 && p[e] > p[i1]) i1 = e;
        float s = p[i0] + p[i1];
        sel[t * 2] = i0; sel[t * 2 + 1] = i1;
        wsel[t * 2] = p[i0] / s; wsel[t * 2 + 1] = p[i1] / s;
        atomicAdd(&counts[i0], 1);
        atomicAdd(&counts[i1], 1);
    }
}

// ---------------- tiny scan over 8 experts ----------------
__global__ void k_scan(const int* __restrict__ counts, int* __restrict__ offs,
                       int* __restrict__ pos) {
    if (threadIdx.x == 0) {
        int o = 0;
        for (int e = 0; e < EE; ++e) { offs[e] = o; o += counts[e]; }
        offs[EE] = o;
    }
    if (threadIdx.x < EE) pos[threadIdx.x] = 0;
}

// ---------------- build compact per-expert token lists ----------------
__global__ void k_fill(const int* __restrict__ sel, const float* __restrict__ wsel,
                       const int* __restrict__ offs, int* __restrict__ pos,
                       int* __restrict__ stok, float* __restrict__ swgt) {
    int t = blockIdx.x * 256 + threadIdx.x;
    if (t >= TT) return;
#pragma unroll
    for (int k = 0; k < 2; ++k) {
        int e = sel[t * 2 + k];
        int p = atomicAdd(&pos[e], 1);
        int slot = offs[e] + p;
        stok[slot] = t;
        swgt[slot] = wsel[t * 2 + k];
    }
}

// ---------------- GEMM1: gated = silu(x@w1^T) * (x@w3^T), fp16 out ----------------
// block tile: 128 tokens x 64 I-cols, BK=32, 4 waves each 64x32, dual accumulators.
__global__ __launch_bounds__(256, 2) void k_gemm1(
        const _Float16* __restrict__ xh, const float* __restrict__ w1,
        const float* __restrict__ w3, const int* __restrict__ counts,
        const int* __restrict__ offs, const int* __restrict__ stok,
        _Float16* __restrict__ gbuf) {
    const int e = blockIdx.z;
    const int cnt = counts[e];
    const int m0 = blockIdx.x * 128;
    if (m0 >= cnt) return;
    const int n0 = blockIdx.y * 64;
    const int off = offs[e];
    const int tid = threadIdx.x;
    const int w = tid >> 6, ln = tid & 63;

    __shared__ __align__(16) _Float16 As[128 * 32];
    __shared__ __align__(16) float   B1s[64 * 32];
    __shared__ __align__(16) float   B3s[64 * 32];

    // A staging: issue j covers rows (j*4+w)*16 .. +15; lane: row += ln>>2, col8 = (ln&3)*8
    const _Float16* aptr[2];
#pragma unroll
    for (int j = 0; j < 2; ++j) {
        int r = (j * 4 + w) * 16 + (ln >> 2);
        int slot = off + m0 + r;
        int cl = off + cnt - 1;
        if (slot > cl) slot = cl;                 // clamp; junk rows masked at store
        int tok = stok[slot];
        aptr[j] = xh + (size_t)tok * HH + (ln & 3) * 8;
    }
    // B staging: issue j covers rows (j*4+w)*8 .. +7; lane: row += ln>>3, col4 = (ln&7)*4
    const float* b1ptr[2];
    const float* b3ptr[2];
#pragma unroll
    for (int j = 0; j < 2; ++j) {
        int r = (j * 4 + w) * 8 + (ln >> 3);
        size_t base = ((size_t)e * II + n0 + r) * HH + (ln & 7) * 4;
        b1ptr[j] = w1 + base;
        b3ptr[j] = w3 + base;
    }

    v4f acc1[4][2], acc3[4][2];
#pragma unroll
    for (int a = 0; a < 4; ++a)
#pragma unroll
        for (int b = 0; b < 2; ++b) {
            acc1[a][b] = (v4f){0.f, 0.f, 0.f, 0.f};
            acc3[a][b] = (v4f){0.f, 0.f, 0.f, 0.f};
        }

    const int wm = (w >> 1) * 64, wn = (w & 1) * 32;
    const int rr = ln & 15, q = ln >> 4;

    for (int kk = 0; kk < HH; kk += 32) {
        __syncthreads();
#pragma unroll
        for (int j = 0; j < 2; ++j) {
            gld16(aptr[j] + kk, &As[(j * 4 + w) * 512]);
            gld16(b1ptr[j] + kk, &B1s[(j * 4 + w) * 256]);
            gld16(b3ptr[j] + kk, &B3s[(j * 4 + w) * 256]);
        }
        __syncthreads();

        v8h af[4], b1f[2], b3f[2];
#pragma unroll
        for (int tn = 0; tn < 2; ++tn) {
            const float4* p1 = (const float4*)&B1s[(wn + tn * 16 + rr) * 32 + q * 8];
            const float4* p3 = (const float4*)&B3s[(wn + tn * 16 + rr) * 32 + q * 8];
            float4 c0 = p1[0], c1 = p1[1], d0 = p3[0], d1 = p3[1];
            v8h b1v, b3v;
            b1v[0] = (_Float16)c0.x; b1v[1] = (_Float16)c0.y; b1v[2] = (_Float16)c0.z; b1v[3] = (_Float16)c0.w;
            b1v[4] = (_Float16)c1.x; b1v[5] = (_Float16)c1.y; b1v[6] = (_Float16)c1.z; b1v[7] = (_Float16)c1.w;
            b3v[0] = (_Float16)d0.x; b3v[1] = (_Float16)d0.y; b3v[2] = (_Float16)d0.z; b3v[3] = (_Float16)d0.w;
            b3v[4] = (_Float16)d1.x; b3v[5] = (_Float16)d1.y; b3v[6] = (_Float16)d1.z; b3v[7] = (_Float16)d1.w;
            b1f[tn] = b1v; b3f[tn] = b3v;
        }
#pragma unroll
        for (int tm = 0; tm < 4; ++tm)
            af[tm] = *(const v8h*)&As[(wm + tm * 16 + rr) * 32 + q * 8];
#pragma unroll
        for (int tm = 0; tm < 4; ++tm)
#pragma unroll
            for (int tn = 0; tn < 2; ++tn) {
                acc1[tm][tn] = __builtin_amdgcn_mfma_f32_16x16x32_f16(af[tm], b1f[tn], acc1[tm][tn], 0, 0, 0);
                acc3[tm][tn] = __builtin_amdgcn_mfma_f32_16x16x32_f16(af[tm], b3f[tn], acc3[tm][tn], 0, 0, 0);
            }
    }

    // epilogue: silu(u)*v -> fp16 gbuf.  C/D: col=lane&15, row=(lane>>4)*4+i (m89)
#pragma unroll
    for (int tm = 0; tm < 4; ++tm) {
        int mbase = wm + tm * 16 + q * 4;
#pragma unroll
        for (int i = 0; i < 4; ++i) {
            int m = m0 + mbase + i;
            if (m < cnt) {
                size_t rowoff = (size_t)(off + m) * II + n0 + wn + rr;
#pragma unroll
                for (int tn = 0; tn < 2; ++tn) {
                    float u = acc1[tm][tn][i];
                    float v = acc3[tm][tn][i];
                    float g = u * (1.f / (1.f + __expf(-u))) * v;
                    gbuf[rowoff + tn * 16] = (_Float16)g;
                }
            }
        }
    }
}

// ---------------- GEMM2: out[t] += w_route * (gated @ w2^T) ----------------
__global__ __launch_bounds__(256, 2) void k_gemm2(
        const _Float16* __restrict__ gbuf, const float* __restrict__ w2,
        const int* __restrict__ counts, const int* __restrict__ offs,
        const int* __restrict__ stok, const float* __restrict__ swgt,
        float* __restrict__ out) {
    const int e = blockIdx.z;
    const int cnt = counts[e];
    const int m0 = blockIdx.x * 128;
    if (m0 >= cnt) return;
    const int n0 = blockIdx.y * 64;
    const int off = offs[e];
    const int tid = threadIdx.x;
    const int w = tid >> 6, ln = tid & 63;

    __shared__ __align__(16) _Float16 As[128 * 32];
    __shared__ __align__(16) float    Bs[64 * 32];

    const _Float16* aptr[2];
#pragma unroll
    for (int j = 0; j < 2; ++j) {
        int r = (j * 4 + w) * 16 + (ln >> 2);
        int m = m0 + r;
        if (m > cnt - 1) m = cnt - 1;
        aptr[j] = gbuf + (size_t)(off + m) * II + (ln & 3) * 8;
    }
    const float* bptr[2];
#pragma unroll
    for (int j = 0; j < 2; ++j) {
        int r = (j * 4 + w) * 8 + (ln >> 3);
        bptr[j] = w2 + ((size_t)e * HH + n0 + r) * II + (ln & 7) * 4;
    }

    v4f acc[4][2];
#pragma unroll
    for (int a = 0; a < 4; ++a)
#pragma unroll
        for (int b = 0; b < 2; ++b) acc[a][b] = (v4f){0.f, 0.f, 0.f, 0.f};

    const int wm = (w >> 1) * 64, wn = (w & 1) * 32;
    const int rr = ln & 15, q = ln >> 4;

    for (int kk = 0; kk < II; kk += 32) {
        __syncthreads();
#pragma unroll
        for (int j = 0; j < 2; ++j) {
            gld16(aptr[j] + kk, &As[(j * 4 + w) * 512]);
            gld16(bptr[j] + kk, &Bs[(j * 4 + w) * 256]);
        }
        __syncthreads();

        v8h af[4], bf[2];
#pragma unroll
        for (int tn = 0; tn < 2; ++tn) {
            const float4* pb = (const float4*)&Bs[(wn + tn * 16 + rr) * 32 + q * 8];
            float4 c0 = pb[0], c1 = pb[1];
            v8h bv;
            bv[0] = (_Float16)c0.x; bv[1] = (_Float16)c0.y; bv[2] = (_Float16)c0.z; bv[3] = (_Float16)c0.w;
            bv[4] = (_Float16)c1.x; bv[5] = (_Float16)c1.y; bv[6] = (_Float16)c1.z; bv[7] = (_Float16)c1.w;
            bf[tn] = bv;
        }
#pragma unroll
        for (int tm = 0; tm < 4; ++tm)
            af[tm] = *(const v8h*)&As[(wm + tm * 16 + rr) * 32 + q * 8];
#pragma unroll
        for (int tm = 0; tm < 4; ++tm)
#pragma unroll
            for (int tn = 0; tn < 2; ++tn)
                acc[tm][tn] = __builtin_amdgcn_mfma_f32_16x16x32_f16(af[tm], bf[tn], acc[tm][tn], 0, 0, 0);
    }

#pragma unroll
    for (int tm = 0; tm < 4; ++tm) {
        int mbase = wm + tm * 16 + q * 4;
#pragma unroll
        for (int i = 0; i < 4; ++i) {
            int m = m0 + mbase + i;
            if (m < cnt) {
                int slot = off + m;
                int t = stok[slot];
                float wg = swgt[slot];
                float* orow = out + (size_t)t * HH + n0 + wn + rr;
#pragma unroll
                for (int tn = 0; tn < 2; ++tn)
                    atomicAdd(&orow[tn * 16], wg * acc[tm][tn][i]);
            }
        }
    }
}

extern "C" void kernel_launch(void* const* d_in, const int* in_sizes, int n_in,
                              void* d_out, int out_size, void* d_ws, size_t ws_size,
                              hipStream_t stream) {
    (void)in_sizes; (void)n_in; (void)out_size; (void)ws_size;
    const float* x  = (const float*)d_in[0];
    const float* gw = (const float*)d_in[1];
    const float* w1 = (const float*)d_in[2];
    const float* w3 = (const float*)d_in[3];
    const float* w2 = (const float*)d_in[4];
    float* out = (float*)d_out;

    // workspace layout (~67 MB)
    char* ws = (char*)d_ws;
    int*   counts = (int*)ws;                    // 8
    int*   pos    = counts + 8;                  // 8
    int*   offs   = pos + 8;                     // 9 (padded to 16)
    int*   sel    = offs + 16;                   // 2048*2
    float* wsel   = (float*)(sel + 2 * TT);      // 2048*2
    int*   stok   = (int*)(wsel + 2 * TT);       // 4096
    float* swgt   = (float*)(stok + 2 * TT);     // 4096
    _Float16* xh   = (_Float16*)(swgt + 2 * TT);           // TT*HH fp16
    _Float16* gbuf = xh + (size_t)TT * HH;                 // 4096*II fp16

    k_zero  <<<4096, 256, 0, stream>>>(out, counts);
    k_cvt   <<<4096, 256, 0, stream>>>(x, xh);
    k_router<<<TT,   256, 0, stream>>>(x, gw, sel, wsel, counts);
    k_scan  <<<1,     64, 0, stream>>>(counts, offs, pos);
    k_fill  <<<TT / 256, 256, 0, stream>>>(sel, wsel, offs, pos, stok, swgt);
    // m-tile fastest-varying -> same-(e,n) blocks dispatch-adjacent -> L3 absorbs weight re-reads
    k_gemm1 <<<dim3(16, II / 64, EE), 256, 0, stream>>>(xh, w1, w3, counts, offs, stok, gbuf);
    k_gemm2 <<<dim3(16, HH / 64, EE), 256, 0, stream>>>(gbuf, w2, counts, offs, stok, swgt, out);
}